// Round 1
// baseline (19716.768 us; speedup 1.0000x reference)
//
#include <hip/hip_runtime.h>
#include <hip/hip_bf16.h>

#define H      1000          // hidden dim
#define HP     1024          // padded hidden (packet elements)
#define TT     8192          // seq len
#define NC     68            // num chars
#define SL     64            // wave size
#define NWAVE  128           // 16 row slices x 8 col chunks
#define PRING  4             // packet ring slots
#define POLL_LIMIT 32768u    // sweeps before declaring the fast path dead
#define TM     16            // t-tile for output gemm
#define GRID_FAST 2048       // oversubscribed launch; cohort self-assembles on XCD 0

typedef unsigned long long u64;
typedef long long ll;

// ---------------------------------------------------------------------------
// FAST PATH (single-XCD edition): the 128-wave cohort self-assembles on XCD 0
// so the per-step all-reduce runs through XCD 0's OWN L2 instead of the MALL.
//
// Assembly: 2048 one-wave blocks launched; each wave reads HW_REG_XCC_ID.
// Blocks not on XCD 0 exit immediately. XCD-0 blocks claim a rank from an
// agent-scope counter; ranks >= 128 exit. Participants never depend on
// non-participants (those retire at once), so dispatch cannot deadlock.
//
// Wave (b = rank>>3, cc = rank&7): lane rl produces row=b*64+rl over cols
// [cc*128, cc*128+128) (w in VGPRs), and consumes elements e0=cc*128+rl,
// e1=e0+64. Per step:
//   1. 128 reg-FMAs -> partial a
//   2. publish: PLAIN (no sc1) global_atomic_add_x2 of ((enc-old)<<16 | 1)
//      into pkt[slot][row]. No sc1 => the RMW executes at XCD 0's local L2
//      (device-incoherent, but every participant is on XCD 0 so the local L2
//      IS the cohort's coherence point). Count (low 16b) and value (high 48b)
//      update in the SAME atomic.
//   3. poll MY two packets with global_load_dwordx2 ... sc0 (bypass per-CU L1,
//      read the L2-fresh line — the tgsplit workgroup-scope contract) until
//      count == expected(want) = 8*((want+3)>>2). Counts are monotone, slots
//      never reset; each slot-use adds exactly 8 counts/element.
//   4. decode fixed point, z = sum + xh + bias, h = tanh(z) (bit-identical
//      across the 16 redundant finalizers), share chunk via 512B LDS.
//
// Ring safety (PRING=4): unchanged from the proven MALL version — a producer
// adding @want+4 completed its poll@want+3, which transitively spans ALL 16
// slices at @want+2, so no poller of `want` can observe extra adds. Value-
// field deltas have zero low 16 bits; count <= 16384 never carries.
//
// Numerics: |partial| < 2 => |enc| < 2^33, sum of 8 < 2^36 << 2^47.
//
// Liveness: if the cohort never completes (XCD starved of blocks, stale
// polls, anything): every poll is bounded by POLL_LIMIT sweeps, the wave
// exits, the cohort unravels, `done` stays < 8 and the proven R3 agent-scope
// fallback recomputes ALL of h_all (it rewrites every row 1..TT). No hang.
// ---------------------------------------------------------------------------
__global__ __launch_bounds__(64, 1) void rnn_fast(
    const int*   __restrict__ x_idx,
    const float* __restrict__ W_xhT,   // NC x H
    const float* __restrict__ W_hh,
    const float* __restrict__ B_h,
    float*       __restrict__ h_all,   // (TT+1) x H
    u64*         __restrict__ pkt,     // [PRING][HP], pre-zeroed
    int*         __restrict__ done,    // completion counter, pre-zeroed
    int*         __restrict__ claim)   // rank counter, pre-zeroed
{
    // --- cohort self-assembly on XCD 0 ---
    unsigned xcc;
    asm volatile("s_getreg_b32 %0, hwreg(HW_REG_XCC_ID)" : "=s"(xcc));
    if ((xcc & 7u) != 0u) return;

    const int rl = threadIdx.x;
    int rank = 0;
    if (rl == 0)
        rank = __hip_atomic_fetch_add(claim, 1, __ATOMIC_RELAXED,
                                      __HIP_MEMORY_SCOPE_AGENT);
    rank = __builtin_amdgcn_readfirstlane(rank);
    if (rank >= NWAVE) return;

    const int b  = rank >> 3;                 // row slice 0..15
    const int cc = rank & 7;                  // col chunk 0..7
    const int row = b * SL + rl;              // producer row
    const int e0  = cc * 128 + rl;            // consumer elements (e0 <= 959)
    const int e1  = e0 + 64;
    const bool rowv = (row < H);
    const bool v1   = (e1 < H);

    // --- 128 W_hh weights -> VGPRs (zero-padded rows/cols >= 1000) ---
    float w[128];
    const float* wrow = W_hh + (size_t)row * H;
    #pragma unroll
    for (int q = 0; q < 32; ++q) {
        const int k = cc * 128 + 4 * q;
        float4 v = make_float4(0.f, 0.f, 0.f, 0.f);
        if (rowv && (k + 3) < H) v = *(const float4*)(wrow + k);
        w[4*q+0] = v.x; w[4*q+1] = v.y; w[4*q+2] = v.z; w[4*q+3] = v.w;
    }
    const float bi0 = B_h[e0];
    const float bi1 = v1 ? B_h[e1] : 0.f;

    __shared__ float sh[128];                 // my h-chunk
    sh[rl]      = h_all[e0];
    sh[64 + rl] = v1 ? h_all[e1] : 0.f;
    asm volatile("s_waitcnt lgkmcnt(0)" ::: "memory");

    int xi = x_idx[0];
    ll old0 = 0, old1 = 0, old2 = 0, old3 = 0;   // per-slot publish memory

#define RSTEP(WANT, SLOT, OLDV)                                               \
    {                                                                         \
        const int want = (WANT);                                              \
        int xi_nxt = xi;                                                      \
        if (want < TT) xi_nxt = x_idx[want];                                  \
        const float xh0 = W_xhT[(size_t)xi * H + e0];                         \
        const float xh1 = v1 ? W_xhT[(size_t)xi * H + e1] : 0.f;              \
        float a0 = 0.f, a1 = 0.f, a2 = 0.f, a3 = 0.f;                         \
        const float4* hb = (const float4*)sh;                                 \
        _Pragma("unroll")                                                     \
        for (int q = 0; q < 32; ++q) {                                        \
            const float4 hv4 = hb[q];                                         \
            a0 += w[4*q+0] * hv4.x;                                           \
            a1 += w[4*q+1] * hv4.y;                                           \
            a2 += w[4*q+2] * hv4.z;                                           \
            a3 += w[4*q+3] * hv4.w;                                           \
        }                                                                     \
        const float a = (a0 + a1) + (a2 + a3);                                \
        const ll ev = (ll)(a * 4294967296.0f);                                \
        const u64 delta = ((u64)(ev - (OLDV)) << 16) | 1ull;                  \
        /* RMW at XCD-0 local L2: no sc1, no return */                        \
        asm volatile("global_atomic_add_x2 %0, %1, off"                       \
                     :: "v"(pkt + (SLOT) * HP + row), "v"(delta)              \
                     : "memory");                                             \
        (OLDV) = ev;                                                          \
        const unsigned expected = 8u * ((unsigned)(want + 3) >> 2);           \
        const u64* q0p = pkt + (SLOT) * HP + e0;                              \
        u64 p0, p1;                                                           \
        unsigned sweeps = 0;                                                  \
        for (;;) {                                                            \
            /* sc0: bypass per-CU L1, read L2-fresh (same-XCD coherent) */    \
            asm volatile(                                                     \
                "global_load_dwordx2 %0, %2, off sc0\n\t"                     \
                "global_load_dwordx2 %1, %3, off sc0\n\t"                     \
                "s_waitcnt vmcnt(0)"                                          \
                : "=&v"(p0), "=&v"(p1)                                        \
                : "v"(q0p), "v"(q0p + 64)                                     \
                : "memory");                                                  \
            const bool ok = ((unsigned)(p0 & 0xFFFFull) == expected) &        \
                            ((unsigned)(p1 & 0xFFFFull) == expected);         \
            if (__all(ok)) break;                                             \
            if (++sweeps > POLL_LIMIT) return;   /* cohort dead: bail out */  \
        }                                                                     \
        const float z0 = (float)((double)((ll)p0 >> 16) *                     \
                                 (1.0 / 4294967296.0)) + xh0 + bi0;           \
        const float z1 = (float)((double)((ll)p1 >> 16) *                     \
                                 (1.0 / 4294967296.0)) + xh1 + bi1;           \
        const float h0v = tanhf(z0);                                          \
        const float h1v = v1 ? tanhf(z1) : 0.f;                               \
        if (want < TT) {                                                      \
            sh[rl]      = h0v;                                                \
            sh[64 + rl] = h1v;                                                \
            asm volatile("s_waitcnt lgkmcnt(0)" ::: "memory");                \
        }                                                                     \
        if (b == cc) {                       /* 8 designated writer waves */  \
            h_all[(size_t)want * H + e0] = h0v;                               \
            if (v1) h_all[(size_t)want * H + e1] = h1v;                       \
        }                                                                     \
        xi = xi_nxt;                                                          \
    }

    for (int tb = 0; tb < TT; tb += PRING) {
        RSTEP(tb + 1, 1, old1)
        RSTEP(tb + 2, 2, old2)
        RSTEP(tb + 3, 3, old3)
        RSTEP(tb + 4, 0, old0)
    }
#undef RSTEP

    if (b == cc && rl == 0)
        __hip_atomic_fetch_add(done, 1, __ATOMIC_RELAXED,
                               __HIP_MEMORY_SCOPE_AGENT);
}

// ---------------------------------------------------------------------------
// FALLBACK: proven R3 agent-scope path (15.2ms). Skipped iff the fast cohort
// fully completed (done == 8) and the fast path was attempted (fail == 0).
// ---------------------------------------------------------------------------
#define FB_RING 4
__global__ __launch_bounds__(64) void rnn_fb(
    const int*   __restrict__ x_idx,
    const float* __restrict__ W_xhT,
    const float* __restrict__ W_hh,
    const float* __restrict__ B_h,
    float*       __restrict__ h_all,
    u64*         __restrict__ pkt,     // FB_RING x 16 x 16 x SL
    const int*   __restrict__ fail,
    const int*   __restrict__ done)
{
    if (__hip_atomic_load(fail, __ATOMIC_RELAXED,
                          __HIP_MEMORY_SCOPE_AGENT) == 0 &&
        __hip_atomic_load(done, __ATOMIC_RELAXED,
                          __HIP_MEMORY_SCOPE_AGENT) == 8)
        return;                               // fast path delivered h_all

    const int rl  = threadIdx.x;
    const int b   = blockIdx.x >> 4;
    const int cc  = blockIdx.x & 15;
    const int row = b * SL + rl;
    const int r   = cc * SL + rl;
    const bool rowv = (row < H);
    const bool rv   = (r < H);

    float w[SL];
    const float* wrow = W_hh + (size_t)row * H;
    #pragma unroll
    for (int q = 0; q < SL / 4; ++q) {
        const int k = cc * SL + 4 * q;
        float4 v = make_float4(0.f, 0.f, 0.f, 0.f);
        if (rowv && (k + 3) < H) v = *(const float4*)(wrow + k);
        w[4*q+0] = v.x; w[4*q+1] = v.y; w[4*q+2] = v.z; w[4*q+3] = v.w;
    }
    const float bh = rv ? B_h[r] : 0.f;

    __shared__ float sh[SL];
    sh[rl] = rv ? h_all[r] : 0.f;
    asm volatile("s_waitcnt lgkmcnt(0)" ::: "memory");

    int xi = x_idx[0];
    for (int t = 0; t < TT; ++t) {
        const unsigned want = (unsigned)(t + 1);
        const int slot = (int)(want & (FB_RING - 1));
        int xi_nxt = xi;
        if (t + 1 < TT) xi_nxt = x_idx[t + 1];
        float xh = 0.f;
        if (rv) xh = W_xhT[(size_t)xi * H + r];

        float a0 = 0.f, a1 = 0.f, a2 = 0.f, a3 = 0.f;
        const float4* hb = (const float4*)sh;
        #pragma unroll
        for (int q = 0; q < SL / 4; ++q) {
            const float4 hv4 = hb[q];
            a0 += w[4*q+0] * hv4.x;
            a1 += w[4*q+1] * hv4.y;
            a2 += w[4*q+2] * hv4.z;
            a3 += w[4*q+3] * hv4.w;
        }
        const float a = (a0 + a1) + (a2 + a3);

        __hip_atomic_store(pkt + (((size_t)slot * 16 + b) * 16 + cc) * SL + rl,
                           ((u64)want << 32) | (u64)__float_as_uint(a),
                           __ATOMIC_RELAXED, __HIP_MEMORY_SCOPE_AGENT);

        const u64* base = pkt + ((size_t)slot * 16 + cc) * 16 * SL + rl;
        u64 p[16];
        for (;;) {
            #pragma unroll
            for (int j = 0; j < 16; ++j)
                p[j] = __hip_atomic_load(base + j * SL, __ATOMIC_RELAXED,
                                         __HIP_MEMORY_SCOPE_AGENT);
            bool ok = true;
            #pragma unroll
            for (int j = 0; j < 16; ++j)
                ok &= ((unsigned)(p[j] >> 32) == want);
            if (__all(ok)) break;
        }

        float s = xh + bh;
        #pragma unroll
        for (int j = 0; j < 16; ++j) s += __uint_as_float((unsigned)p[j]);
        const float hv = rv ? tanhf(s) : 0.f;
        if (b == cc && rv) h_all[(size_t)want * H + r] = hv;
        sh[rl] = hv;
        asm volatile("s_waitcnt lgkmcnt(0)" ::: "memory");
        xi = xi_nxt;
    }
}

// ---------------------------------------------------------------------------
__global__ __launch_bounds__(256) void transpose_wxh(
    const float* __restrict__ W_xh, float* __restrict__ W_xhT)
{
    const int idx = blockIdx.x * 256 + threadIdx.x;
    if (idx < NC * H) {
        const int c = idx / H, r = idx % H;
        W_xhT[idx] = W_xh[r * NC + c];
    }
}

__global__ __launch_bounds__(256) void transpose_why(
    const float* __restrict__ W_hy, float* __restrict__ WhyT)
{
    const int idx = blockIdx.x * 256 + threadIdx.x;
    if (idx < NC * H) {
        const int k = idx / NC, n = idx % NC;
        WhyT[idx] = W_hy[n * H + k];
    }
}

__global__ __launch_bounds__(256) void out_gemm(
    const float* __restrict__ h_all,
    const float* __restrict__ WhyT,   // padded by >=16 floats
    float*       __restrict__ out)
{
    __shared__ float hs[TM * H];      // 64000 B
    const int t0 = blockIdx.x * TM;
    const int nt = min(TM, (TT + 1) - t0);

    const float4* src = (const float4*)(h_all + (size_t)t0 * H);
    const int total4 = nt * H / 4;
    for (int i = threadIdx.x; i < total4; i += 256)
        ((float4*)hs)[i] = src[i];
    __syncthreads();

    const int tl = threadIdx.x >> 4;
    const int ng = threadIdx.x & 15;
    if (tl < nt) {
        float acc0 = 0.f, acc1 = 0.f, acc2 = 0.f, acc3 = 0.f, acc4 = 0.f;
        const float* hrow = hs + tl * H;
        #pragma unroll 4
        for (int k = 0; k < H; ++k) {
            const float hv = hrow[k];
            const float* wr = WhyT + k * NC + ng;
            acc0 += hv * wr[0];
            acc1 += hv * wr[16];
            acc2 += hv * wr[32];
            acc3 += hv * wr[48];
            acc4 += hv * wr[64];
        }
        float* orow = out + (size_t)(t0 + tl) * NC + ng;
        orow[0]  = acc0;
        orow[16] = acc1;
        orow[32] = acc2;
        orow[48] = acc3;
        if (ng < 4) orow[64] = acc4;
    }
}

// ---------------------------------------------------------------------------
extern "C" void kernel_launch(void* const* d_in, const int* in_sizes, int n_in,
                              void* d_out, int out_size, void* d_ws, size_t ws_size,
                              hipStream_t stream)
{
    const int*   x_idx = (const int*)  d_in[0];
    const float* h0    = (const float*)d_in[1];
    const float* W_xh  = (const float*)d_in[2];
    const float* W_hh  = (const float*)d_in[3];
    const float* W_hy  = (const float*)d_in[4];
    const float* B_h   = (const float*)d_in[5];
    float* out = (float*)d_out;

    char* ws = (char*)d_ws;
    size_t off = 0;
    auto take = [&](size_t bytes) {
        void* p = ws + off;
        off = (off + bytes + 255) & ~(size_t)255;
        return p;
    };
    float* h_all  = (float*)take((size_t)(TT + 1) * H * sizeof(float));
    float* WhyT   = (float*)take((size_t)(NC * H + 32) * sizeof(float));
    float* W_xhT  = (float*)take((size_t)(NC * H) * sizeof(float));
    const size_t fb_bytes = (size_t)FB_RING * 16 * 16 * SL * sizeof(u64);
    u64*   pkt_fb = (u64*)take(fb_bytes);
    int*   fail   = (int*)take(64);
    int*   done   = (int*)take(64);
    int*   claim  = (int*)take(64);
    const size_t fp_bytes = (size_t)PRING * HP * sizeof(u64);   // 32 KB
    u64*   pkt_fp = (u64*)take(fp_bytes);
    const size_t need_fast = off;

    hipMemcpyAsync(h_all, h0, H * sizeof(float),
                   hipMemcpyDeviceToDevice, stream);
    transpose_wxh<<<(NC * H + 255) / 256, 256, 0, stream>>>(W_xh, W_xhT);
    transpose_why<<<(NC * H + 255) / 256, 256, 0, stream>>>(W_hy, WhyT);

    hipMemsetAsync(pkt_fb, 0, fb_bytes, stream);
    hipMemsetAsync(done, 0, 64, stream);
    if (ws_size >= need_fast) {
        hipMemsetAsync(pkt_fp, 0, fp_bytes, stream);
        hipMemsetAsync(fail, 0, 64, stream);
        hipMemsetAsync(claim, 0, 64, stream);
        rnn_fast<<<GRID_FAST, SL, 0, stream>>>(x_idx, W_xhT, W_hh, B_h,
                                               h_all, pkt_fp, done, claim);
    } else {
        hipMemsetAsync(fail, 1, 4, stream);    // force fallback
    }
    rnn_fb<<<256, SL, 0, stream>>>(x_idx, W_xhT, W_hh, B_h,
                                   h_all, pkt_fb, fail, done);
    out_gemm<<<(TT + 1 + TM - 1) / TM, 256, 0, stream>>>(h_all, WhyT, out);
}